// Round 1
// baseline (1874.667 us; speedup 1.0000x reference)
//
#include <hip/hip_runtime.h>

#define BB 16
#define LL 2048
#define HH 512
#define NN2 32
#define NLAY 4
#define OUTD 256
#define BLM (BB*LL)   // 32768 rows
#define CL (LL/2)     // chunk length 1024

// ---------------- embedding gather: h[b,l,:] = emb[x[b,l],:] ----------------
__global__ __launch_bounds__(256) void k_embed(const int* __restrict__ x,
    const float* __restrict__ emb, float* __restrict__ h) {
  int idx = blockIdx.x * 256 + threadIdx.x;      // one float4 per thread
  int j4 = idx & (HH/4 - 1);                     // 0..127
  int bl = idx >> 7;
  int tok = x[bl];
  reinterpret_cast<float4*>(h)[idx] =
      reinterpret_cast<const float4*>(emb)[tok * (HH/4) + j4];
}

// ---------------- per-layer SSM parameters: lam, 2*coef --------------------
// par[h*32+n] = (lam_re, lam_im, 2*coef_re, 2*coef_im)
__global__ __launch_bounds__(256) void k_params(const float* __restrict__ log_dt,
    const float* __restrict__ log_A_real, const float* __restrict__ A_imag,
    const float* __restrict__ C_re, const float* __restrict__ C_im,
    int layer, float4* __restrict__ par) {
  int idx = blockIdx.x * 256 + threadIdx.x;      // h*32+n, total 16384
  int h = idx >> 5;
  int o = layer * HH * NN2 + idx;
  float dt  = expf(log_dt[layer * HH + h]);
  float Are = -expf(log_A_real[o]);
  float Aim = A_imag[o];
  float dre = Are * dt, dim = Aim * dt;
  float er = expf(dre);
  float lr = er * cosf(dim), li = er * sinf(dim);
  // coef = C * (lam - 1) / A
  float inv  = 1.0f / (Are * Are + Aim * Aim);
  float numr = lr - 1.0f, numi = li;
  float qr = (numr * Are + numi * Aim) * inv;
  float qi = (numi * Are - numr * Aim) * inv;
  float cr = C_re[o], ci = C_im[o];
  par[idx] = make_float4(lr, li, 2.0f * (cr * qr - ci * qi),
                                 2.0f * (cr * qi + ci * qr));
}

// ---------------- fused fp32 GEMM ------------------------------------------
// EPI==1: out = act1(A@W + bias + A)  with act1(t) = t<0 ? 2t : 4t   (N==512)
// EPI==0: out = A@W + bias                                           (final)
template<int EPI>
__global__ __launch_bounds__(256) void k_gemm(const float* __restrict__ A,
    const float* __restrict__ W, const float* __restrict__ bias,
    float* __restrict__ out, int N) {
  __shared__ float As[16][68];   // [k][m], stride 68 keeps 16B alignment
  __shared__ float Bs[16][64];   // [k][n]
  const int tid = threadIdx.x;
  const int m0 = blockIdx.x * 64, n0 = blockIdx.y * 64;
  const int tx = tid & 15, ty = tid >> 4;
  const int am = tid >> 2, ak = (tid & 3) << 2;   // A-load: row am, k-offset ak
  const int bk = tid >> 4, bn = (tid & 15) << 2;  // B-load: k-row bk, col bn
  const float* Ap = A + (size_t)(m0 + am) * 512 + ak;
  const float* Wp = W + (size_t)bk * N + n0 + bn;
  float acc[4][4] = {{0.f}};
  for (int k0 = 0; k0 < 512; k0 += 16) {
    float4 av = *reinterpret_cast<const float4*>(Ap + k0);
    float4 bv = *reinterpret_cast<const float4*>(Wp + (size_t)k0 * N);
    __syncthreads();
    As[ak + 0][am] = av.x; As[ak + 1][am] = av.y;
    As[ak + 2][am] = av.z; As[ak + 3][am] = av.w;
    *reinterpret_cast<float4*>(&Bs[bk][bn]) = bv;
    __syncthreads();
#pragma unroll
    for (int kk = 0; kk < 16; ++kk) {
      float4 a4 = *reinterpret_cast<const float4*>(&As[kk][ty << 2]);
      float4 b4 = *reinterpret_cast<const float4*>(&Bs[kk][tx << 2]);
      float a_[4] = {a4.x, a4.y, a4.z, a4.w};
      float b_[4] = {b4.x, b4.y, b4.z, b4.w};
#pragma unroll
      for (int i = 0; i < 4; ++i)
#pragma unroll
        for (int j = 0; j < 4; ++j)
          acc[i][j] = fmaf(a_[i], b_[j], acc[i][j]);
    }
  }
  float4 bi = *reinterpret_cast<const float4*>(&bias[n0 + (tx << 2)]);
  float b_[4] = {bi.x, bi.y, bi.z, bi.w};
#pragma unroll
  for (int i = 0; i < 4; ++i) {
    int m = m0 + (ty << 2) + i;
    float r[4];
    if (EPI) {
      float4 hv = *reinterpret_cast<const float4*>(&A[(size_t)m * 512 + n0 + (tx << 2)]);
      float h_[4] = {hv.x, hv.y, hv.z, hv.w};
#pragma unroll
      for (int j = 0; j < 4; ++j) {
        float t = acc[i][j] + b_[j] + h_[j];
        r[j] = t < 0.f ? 2.f * t : 4.f * t;
      }
    } else {
#pragma unroll
      for (int j = 0; j < 4; ++j) r[j] = acc[i][j] + b_[j];
    }
    *reinterpret_cast<float4*>(&out[(size_t)m * N + n0 + (tx << 2)]) =
        make_float4(r[0], r[1], r[2], r[3]);
  }
}

// ---------------- SSM pass A: raw end-state of chunk 0 ---------------------
// thread = (b, h, n); g[l] = lam*g[l-1] + u[l] over l = 0..CL-1
__global__ __launch_bounds__(256) void k_sa(const float* __restrict__ U,
    const float4* __restrict__ par, float2* __restrict__ st) {
  int tid = threadIdx.x;
  int n = tid & 31, hs = tid >> 5;               // 8 h per block
  int bi = blockIdx.x;
  int b = bi >> 6, h = ((bi & 63) << 3) + hs;
  float4 p = par[(h << 5) + n];
  float lr = p.x, li = p.y;
  const float* Up = U + (size_t)b * LL * HH + h;
  float sr = 0.f, si = 0.f;
  auto step = [&](float uv) {
    float nsr = fmaf(lr, sr, fmaf(-li, si, uv));
    si = fmaf(lr, si, li * sr);
    sr = nsr;
  };
  float u0 = Up[0], u1 = Up[HH], u2 = Up[2 * HH], u3 = Up[3 * HH];
  for (int lg = 0; lg < CL / 4; ++lg) {
    const float* nx = Up + (size_t)(lg * 4 + 4) * HH;  // prefetch (stays in U)
    float v0 = nx[0], v1 = nx[HH], v2 = nx[2 * HH], v3 = nx[3 * HH];
    step(u0); step(u1); step(u2); step(u3);
    u0 = v0; u1 = v1; u2 = v2; u3 = v3;
  }
  st[((size_t)b * HH + h) * NN2 + n] = make_float2(sr, si);
}

// ---------------- SSM pass B: folded recurrence + epilogue -----------------
// thread = (b, h, chunk, q), q owns 8 of 32 states. t = (2coef)*g.
// y = Sum Re t; out = act2(y + (D+1)*u), act2(t) = t<0 ? 2t : 4t
__global__ __launch_bounds__(256) void k_sb(const float* __restrict__ U,
    const float4* __restrict__ par, const float2* __restrict__ st,
    const float* __restrict__ D, float* __restrict__ Hout) {
  int tid = threadIdx.x;
  int q = tid & 3, hs = tid >> 2;                // 64 h per block
  int bi = blockIdx.x;
  int hb = bi & 7, c = (bi >> 3) & 1, b = bi >> 4;
  int h = (hb << 6) + hs;
  float lr[8], li[8], cr[8], ci[8], tr[8], ti[8];
#pragma unroll
  for (int j = 0; j < 8; ++j) {
    float4 p = par[(h << 5) + (q << 3) + j];
    lr[j] = p.x; li[j] = p.y; cr[j] = p.z; ci[j] = p.w;
    tr[j] = 0.f; ti[j] = 0.f;
  }
  if (c) {
#pragma unroll
    for (int j = 0; j < 8; ++j) {
      float2 s = st[((size_t)b * HH + h) * NN2 + (q << 3) + j];
      tr[j] = cr[j] * s.x - ci[j] * s.y;
      ti[j] = cr[j] * s.y + ci[j] * s.x;
    }
  }
  float dp1 = D[h] + 1.0f;
  size_t base = ((size_t)b * LL + (size_t)c * CL) * HH + h;
  const float* Up = U + base;
  float* Op = Hout + base;
  auto step = [&](float uv, float* dst) {
    float ys = 0.f;
#pragma unroll
    for (int j = 0; j < 8; ++j) {
      float ntr = fmaf(lr[j], tr[j], fmaf(-li[j], ti[j], cr[j] * uv));
      ti[j] = fmaf(lr[j], ti[j], fmaf(li[j], tr[j], ci[j] * uv));
      tr[j] = ntr;
      ys += ntr;
    }
    ys += __shfl_xor(ys, 1);
    ys += __shfl_xor(ys, 2);
    float t4 = fmaf(dp1, uv, ys);
    *dst = t4 < 0.f ? 2.f * t4 : 4.f * t4;    // all 4 q-lanes store same value
  };
  float u0 = Up[0], u1 = Up[HH], u2 = Up[2 * HH], u3 = Up[3 * HH];
  for (int lg = 0; lg < CL / 4; ++lg) {
    const float* nx = Up + (size_t)(lg * 4 + 4) * HH;  // last prefetch lands in par region: harmless
    float v0 = nx[0], v1 = nx[HH], v2 = nx[2 * HH], v3 = nx[3 * HH];
    float* op = Op + (size_t)(lg * 4) * HH;
    step(u0, op); step(u1, op + HH); step(u2, op + 2 * HH); step(u3, op + 3 * HH);
    u0 = v0; u1 = v1; u2 = v2; u3 = v3;
  }
}

// ---------------------------------------------------------------------------
extern "C" void kernel_launch(void* const* d_in, const int* in_sizes, int n_in,
                              void* d_out, int out_size, void* d_ws, size_t ws_size,
                              hipStream_t stream) {
  const int*   x      = (const int*)d_in[0];
  const float* emb    = (const float*)d_in[1];
  const float* Ws     = (const float*)d_in[2];
  const float* bs     = (const float*)d_in[3];
  const float* log_dt = (const float*)d_in[4];
  const float* lAr    = (const float*)d_in[5];
  const float* Aim    = (const float*)d_in[6];
  const float* Cre    = (const float*)d_in[7];
  const float* Cim    = (const float*)d_in[8];
  const float* Ds     = (const float*)d_in[9];
  const float* Wo     = (const float*)d_in[10];
  const float* bo     = (const float*)d_in[11];

  float*  bufA = (float*)d_ws;                       // h   (64 MB)
  float*  bufU = bufA + (size_t)BLM * HH;            // u   (64 MB)
  float4* par  = (float4*)(bufU + (size_t)BLM * HH); // 256 KB
  float2* st   = (float2*)(par + HH * NN2);          // 2 MB

  k_embed<<<BLM * HH / 4 / 256, 256, 0, stream>>>(x, emb, bufA);
  for (int i = 0; i < NLAY; ++i) {
    k_params<<<HH * NN2 / 256, 256, 0, stream>>>(log_dt, lAr, Aim, Cre, Cim, i, par);
    k_gemm<1><<<dim3(BLM / 64, HH / 64), 256, 0, stream>>>(
        bufA, Ws + (size_t)i * HH * HH, bs + i * HH, bufU, HH);
    k_sa<<<BB * HH / 8, 256, 0, stream>>>(bufU, par, st);
    k_sb<<<BB * 2 * 8, 256, 0, stream>>>(bufU, par, st, Ds + i * HH, bufA);
  }
  k_gemm<0><<<dim3(BLM / 64, OUTD / 64), 256, 0, stream>>>(
      bufA, Wo, bo, (float*)d_out, OUTD);
}

// Round 3
// 1210.428 us; speedup vs baseline: 1.5488x; 1.5488x over previous
//
#include <hip/hip_runtime.h>

#define BB 16
#define LL 2048
#define HH 512
#define NN2 32
#define NLAY 4
#define OUTD 256
#define BLM (BB*LL)                 // 32768 rows
#define NELEM ((size_t)BLM*HH)      // 16.78M activations
#define NC 8                        // SSM time chunks
#define LC (LL/NC)                  // 256

typedef __attribute__((ext_vector_type(8))) short s8v;   // 8 bf16 (4 VGPR)
typedef __attribute__((ext_vector_type(4))) float f4v;   // MFMA acc

__device__ __forceinline__ unsigned short f2bf(float f) {
  unsigned u = __float_as_uint(f);
  return (unsigned short)((u + 0x7fffu + ((u >> 16) & 1u)) >> 16);  // RNE
}
__device__ __forceinline__ float bf2f(unsigned short h) {
  return __uint_as_float((unsigned)h << 16);
}
__device__ __forceinline__ void gload16(const void* g, void* l) {
  __builtin_amdgcn_global_load_lds(
      (const __attribute__((address_space(1))) unsigned int*)g,
      (__attribute__((address_space(3))) unsigned int*)l, 16, 0, 0);
}

// ---------------- embedding gather -> bf16 hi/lo split ---------------------
__global__ __launch_bounds__(256) void k_embed(const int* __restrict__ x,
    const float* __restrict__ emb, unsigned short* __restrict__ Ahi,
    unsigned short* __restrict__ Alo) {
  int idx = blockIdx.x * 256 + threadIdx.x;      // one float4-group
  int j4 = idx & 127;
  int bl = idx >> 7;
  int tok = x[bl];
  float4 v = reinterpret_cast<const float4*>(emb)[tok * 128 + j4];
  unsigned short h0 = f2bf(v.x), h1 = f2bf(v.y), h2 = f2bf(v.z), h3 = f2bf(v.w);
  unsigned short l0 = f2bf(v.x - bf2f(h0)), l1 = f2bf(v.y - bf2f(h1));
  unsigned short l2 = f2bf(v.z - bf2f(h2)), l3 = f2bf(v.w - bf2f(h3));
  uint2 hp = make_uint2((unsigned)h0 | ((unsigned)h1 << 16),
                        (unsigned)h2 | ((unsigned)h3 << 16));
  uint2 lp = make_uint2((unsigned)l0 | ((unsigned)l1 << 16),
                        (unsigned)l2 | ((unsigned)l3 << 16));
  *reinterpret_cast<uint2*>(&Ahi[(size_t)idx * 4]) = hp;
  *reinterpret_cast<uint2*>(&Alo[(size_t)idx * 4]) = lp;
}

// ---------------- weight transpose + hi/lo split: Wt[n][k] = W[k][n] -------
__global__ __launch_bounds__(256) void k_trans(const float* __restrict__ W, int N,
    unsigned short* __restrict__ th, unsigned short* __restrict__ tl) {
  int t = blockIdx.x * 256 + threadIdx.x;        // over N*512, k fastest
  int k = t & 511, n = t >> 9;
  float v = W[(size_t)k * N + n];
  unsigned short hi = f2bf(v);
  th[(size_t)n * 512 + k] = hi;
  tl[(size_t)n * 512 + k] = f2bf(v - bf2f(hi));
}

// ---------------- per-layer SSM parameters ---------------------------------
__global__ __launch_bounds__(256) void k_params(const float* __restrict__ log_dt,
    const float* __restrict__ log_A_real, const float* __restrict__ A_imag,
    const float* __restrict__ C_re, const float* __restrict__ C_im,
    int layer, float4* __restrict__ par) {
  int idx = blockIdx.x * 256 + threadIdx.x;      // h*32+n
  int h = idx >> 5;
  int o = layer * HH * NN2 + idx;
  float dt  = expf(log_dt[layer * HH + h]);
  float Are = -expf(log_A_real[o]);
  float Aim = A_imag[o];
  float er = expf(Are * dt);
  float lr = er * cosf(Aim * dt), li = er * sinf(Aim * dt);
  float inv  = 1.0f / (Are * Are + Aim * Aim);
  float numr = lr - 1.0f, numi = li;
  float qr = (numr * Are + numi * Aim) * inv;
  float qi = (numi * Are - numr * Aim) * inv;
  float cr = C_re[o], ci = C_im[o];
  par[idx] = make_float4(lr, li, 2.0f * (cr * qr - ci * qi),
                                 2.0f * (cr * qi + ci * qr));
}

// ---------------- split-bf16 MFMA GEMM, 128x128 tile, BK=32 ----------------
// C = A@W (+bias [+resid, act]) with A ~ Ahi+Alo, W ~ Bhi+Blo (B stored N x K).
// LDS is fragment-ordered: frag f (16 rows x 32 k) = 64 lanes x 16B, lane l
// holds rows f*16+(l&15), k (l>>4)*8..+7 -> linear global_load_lds dst and
// conflict-free ds_read_b128.
template<int EPI>
__global__ __launch_bounds__(256) void k_gemm(
    const unsigned short* __restrict__ Ahi, const unsigned short* __restrict__ Alo,
    const unsigned short* __restrict__ Bhi, const unsigned short* __restrict__ Blo,
    const float* __restrict__ bias, float* __restrict__ Out, int N) {
  __shared__ short lds[16384];                   // 32KB: AH|AL|BH|BL (8KB each)
  const int tid = threadIdx.x;
  const int lane = tid & 63, w = tid >> 6;
  const int wr = w >> 1, wc = w & 1;             // wave -> 64x64 quadrant
  const int m0 = blockIdx.y * 128, n0 = blockIdx.x * 128;
  const int lm = lane & 15, lk = lane >> 4;

  const unsigned short* ga[2][2]; const unsigned short* gb[2][2];
  short *da[2][2], *db[2][2];
#pragma unroll
  for (int f2 = 0; f2 < 2; ++f2) {
    int f = w * 2 + f2;                          // frag 0..7
    size_t ra = (size_t)(m0 + f * 16 + lm) * 512 + lk * 8;
    size_t rb = (size_t)(n0 + f * 16 + lm) * 512 + lk * 8;
    ga[0][f2] = Ahi + ra; ga[1][f2] = Alo + ra;
    gb[0][f2] = Bhi + rb; gb[1][f2] = Blo + rb;
    da[0][f2] = &lds[f * 512 + lane * 8];
    da[1][f2] = &lds[4096 + f * 512 + lane * 8];
    db[0][f2] = &lds[8192 + f * 512 + lane * 8];
    db[1][f2] = &lds[12288 + f * 512 + lane * 8];
  }
  f4v acc[4][4];
#pragma unroll
  for (int i = 0; i < 4; ++i)
#pragma unroll
    for (int j = 0; j < 4; ++j) acc[i][j] = (f4v){0.f, 0.f, 0.f, 0.f};

  for (int kt = 0; kt < 16; ++kt) {
#pragma unroll
    for (int f2 = 0; f2 < 2; ++f2) {
      gload16(ga[0][f2] + kt * 32, da[0][f2]);
      gload16(ga[1][f2] + kt * 32, da[1][f2]);
      gload16(gb[0][f2] + kt * 32, db[0][f2]);
      gload16(gb[1][f2] + kt * 32, db[1][f2]);
    }
    __syncthreads();                              // compiler drains vmcnt here
    s8v ah[4], al[4], bh[4], bl[4];
#pragma unroll
    for (int i = 0; i < 4; ++i) {
      ah[i] = *(const s8v*)&lds[(wr * 4 + i) * 512 + lane * 8];
      al[i] = *(const s8v*)&lds[4096 + (wr * 4 + i) * 512 + lane * 8];
      bh[i] = *(const s8v*)&lds[8192 + (wc * 4 + i) * 512 + lane * 8];
      bl[i] = *(const s8v*)&lds[12288 + (wc * 4 + i) * 512 + lane * 8];
    }
#pragma unroll
    for (int mi = 0; mi < 4; ++mi)
#pragma unroll
      for (int ni = 0; ni < 4; ++ni) {
        acc[mi][ni] = __builtin_amdgcn_mfma_f32_16x16x32_bf16(ah[mi], bh[ni], acc[mi][ni], 0, 0, 0);
        acc[mi][ni] = __builtin_amdgcn_mfma_f32_16x16x32_bf16(al[mi], bh[ni], acc[mi][ni], 0, 0, 0);
        acc[mi][ni] = __builtin_amdgcn_mfma_f32_16x16x32_bf16(ah[mi], bl[ni], acc[mi][ni], 0, 0, 0);
      }
    __syncthreads();
  }
  // epilogue: C/D layout col=lane&15, row=(lane>>4)*4+reg
  float bb[4];
#pragma unroll
  for (int ni = 0; ni < 4; ++ni) bb[ni] = bias[n0 + wc * 64 + ni * 16 + lm];
#pragma unroll
  for (int mi = 0; mi < 4; ++mi) {
#pragma unroll
    for (int r = 0; r < 4; ++r) {
      int row = m0 + wr * 64 + mi * 16 + lk * 4 + r;
      float* po = Out + (size_t)row * N;
      const unsigned short* ph = Ahi + (size_t)row * 512;
      const unsigned short* pl = Alo + (size_t)row * 512;
#pragma unroll
      for (int ni = 0; ni < 4; ++ni) {
        int col = n0 + wc * 64 + ni * 16 + lm;
        float t = acc[mi][ni][r] + bb[ni];
        if (EPI) {
          t += bf2f(ph[col]) + bf2f(pl[col]);     // resid = hi+lo (err 2^-18)
          t = t < 0.f ? 2.f * t : 4.f * t;        // relu+res, x2
        }
        po[col] = t;
      }
    }
  }
}

// ---------------- SSM pass A: chunk-local raw states (chunks 0..6) ---------
__global__ __launch_bounds__(256) void k_sa(const float* __restrict__ U,
    const float4* __restrict__ par, float2* __restrict__ st) {
  int tid = threadIdx.x;
  int n = tid & 31, hs = tid >> 5;               // 8 h per block
  int hb = blockIdx.x, c = blockIdx.y, b = blockIdx.z;
  int h = (hb << 3) + hs;
  float4 p = par[(h << 5) + n];
  float lr = p.x, li = p.y;
  const float* Up = U + ((size_t)b * LL + (size_t)c * LC) * HH + h;
  float sr = 0.f, si = 0.f;
  auto step = [&](float uv) {
    float nsr = fmaf(lr, sr, fmaf(-li, si, uv));
    si = fmaf(lr, si, li * sr);
    sr = nsr;
  };
  float u0 = Up[0], u1 = Up[HH], u2 = Up[2 * HH], u3 = Up[3 * HH];
  for (int lg = 0; lg < LC / 4; ++lg) {
    const float* nx = Up + (size_t)(lg * 4 + 4) * HH;   // c<=6: stays in U
    float v0 = nx[0], v1 = nx[HH], v2 = nx[2 * HH], v3 = nx[3 * HH];
    step(u0); step(u1); step(u2); step(u3);
    u0 = v0; u1 = v1; u2 = v2; u3 = v3;
  }
  st[(((size_t)b * 7 + c) * HH + h) * NN2 + n] = make_float2(sr, si);
}

// ---------------- fold: prefix-scan chunk states (in place, shifted) -------
// after: slot c holds raw state at START of chunk c+1.
__global__ __launch_bounds__(256) void k_fold(const float4* __restrict__ par,
    float2* __restrict__ st) {
  int t = blockIdx.x * 256 + threadIdx.x;        // 262144 = b*16384 + h*32 + n
  int hn = t & 16383;
  int b = t >> 14;
  float4 p = par[hn];
  float ar = p.x, ai = p.y;
#pragma unroll
  for (int s = 0; s < 8; ++s) { float nr = ar * ar - ai * ai; ai = 2.f * ar * ai; ar = nr; }  // lam^256
  float gr = 0.f, gi = 0.f;
  size_t idx = (size_t)b * 7 * 16384 + hn;
  for (int c = 0; c < 7; ++c) {
    float2 s = st[idx + (size_t)c * 16384];
    float ngr = fmaf(ar, gr, fmaf(-ai, gi, s.x));
    gi = fmaf(ar, gi, fmaf(ai, gr, s.y));
    gr = ngr;
    st[idx + (size_t)c * 16384] = make_float2(gr, gi);
  }
}

// ---------------- SSM pass B: folded recurrence + epilogue -> bf16 hi/lo ---
// thread = (b, h, chunk, q); q owns 8 of 32 states; after the shfl reduce all
// 4 q-lanes hold the step's result, so lane q stores step q of each 4-group.
__global__ __launch_bounds__(256) void k_sb(const float* __restrict__ U,
    const float4* __restrict__ par, const float2* __restrict__ st,
    const float* __restrict__ D, unsigned short* __restrict__ Hhi,
    unsigned short* __restrict__ Hlo) {
  int tid = threadIdx.x;
  int q = tid & 3, hs = tid >> 2;                // 64 h per block, 4 q-lanes
  int hb = blockIdx.x, c = blockIdx.y, b = blockIdx.z;
  int h = (hb << 6) + hs;
  float lr[8], li[8], cr[8], ci[8], tr[8], ti[8];
#pragma unroll
  for (int j = 0; j < 8; ++j) {
    float4 p = par[(h << 5) + (q << 3) + j];
    lr[j] = p.x; li[j] = p.y; cr[j] = p.z; ci[j] = p.w;
    tr[j] = 0.f; ti[j] = 0.f;
  }
  if (c > 0) {
#pragma unroll
    for (int j = 0; j < 8; ++j) {
      float2 s = st[(((size_t)b * 7 + (c - 1)) * HH + h) * NN2 + (q << 3) + j];
      tr[j] = cr[j] * s.x - ci[j] * s.y;
      ti[j] = cr[j] * s.y + ci[j] * s.x;
    }
  }
  float dp1 = D[h] + 1.0f;
  size_t base = ((size_t)b * LL + (size_t)c * LC) * HH + h;
  const float* Up = U + base;
  auto step = [&](float uv) -> float {
    float ys = 0.f;
#pragma unroll
    for (int j = 0; j < 8; ++j) {
      float ntr = fmaf(lr[j], tr[j], fmaf(-li[j], ti[j], cr[j] * uv));
      ti[j] = fmaf(lr[j], ti[j], fmaf(li[j], tr[j], ci[j] * uv));
      tr[j] = ntr;
      ys += ntr;
    }
    ys += __shfl_xor(ys, 1);
    ys += __shfl_xor(ys, 2);
    float t4 = fmaf(dp1, uv, ys);
    return t4 < 0.f ? 2.f * t4 : 4.f * t4;
  };
  float u0 = Up[0], u1 = Up[HH], u2 = Up[2 * HH], u3 = Up[3 * HH];
  for (int lg = 0; lg < LC / 4; ++lg) {
    const float* nx = Up + (size_t)(lg * 4 + 4) * HH;  // tail prefetch lands in ws: harmless
    float v0 = nx[0], v1 = nx[HH], v2 = nx[2 * HH], v3 = nx[3 * HH];
    float r0 = step(u0), r1 = step(u1), r2 = step(u2), r3 = step(u3);
    // all q-lanes hold identical r0..r3; lane q stores step q's output
    float rq = q == 0 ? r0 : q == 1 ? r1 : q == 2 ? r2 : r3;
    size_t o = base + (size_t)(lg * 4 + q) * HH;
    unsigned short hi = f2bf(rq);
    Hhi[o] = hi;
    Hlo[o] = f2bf(rq - bf2f(hi));
    u0 = v0; u1 = v1; u2 = v2; u3 = v3;
  }
}

// ---------------------------------------------------------------------------
extern "C" void kernel_launch(void* const* d_in, const int* in_sizes, int n_in,
                              void* d_out, int out_size, void* d_ws, size_t ws_size,
                              hipStream_t stream) {
  const int*   x      = (const int*)d_in[0];
  const float* emb    = (const float*)d_in[1];
  const float* Ws     = (const float*)d_in[2];
  const float* bs     = (const float*)d_in[3];
  const float* log_dt = (const float*)d_in[4];
  const float* lAr    = (const float*)d_in[5];
  const float* Aim    = (const float*)d_in[6];
  const float* Cre    = (const float*)d_in[7];
  const float* Cim    = (const float*)d_in[8];
  const float* Ds     = (const float*)d_in[9];
  const float* Wo     = (const float*)d_in[10];
  const float* bo     = (const float*)d_in[11];

  float*          bufU   = (float*)d_ws;                       // 67.1 MB
  unsigned short* bufAhi = (unsigned short*)(bufU + NELEM);    // 33.6 MB
  unsigned short* bufAlo = bufAhi + NELEM;                     // 33.6 MB
  float4*         par    = (float4*)(bufAlo + NELEM);          // 256 KB
  float2*         st     = (float2*)(par + HH * NN2);          // 14.7 MB
  unsigned short* wth    = (unsigned short*)(st + (size_t)BB * 7 * HH * NN2);  // 512 KB
  unsigned short* wtl    = wth + 512 * 512;                    // 512 KB

  k_embed<<<(int)(NELEM / 4 / 256), 256, 0, stream>>>(x, emb, bufAhi, bufAlo);
  for (int i = 0; i < NLAY; ++i) {
    k_params<<<HH * NN2 / 256, 256, 0, stream>>>(log_dt, lAr, Aim, Cre, Cim, i, par);
    k_trans<<<HH * 512 / 256, 256, 0, stream>>>(Ws + (size_t)i * HH * HH, HH, wth, wtl);
    k_gemm<1><<<dim3(HH / 128, BLM / 128), 256, 0, stream>>>(
        bufAhi, bufAlo, wth, wtl, bs + i * HH, bufU, HH);
    k_sa<<<dim3(64, 7, BB), 256, 0, stream>>>(bufU, par, st);
    k_fold<<<BB * HH * NN2 / 256, 256, 0, stream>>>(par, st);
    k_sb<<<dim3(8, NC, BB), 256, 0, stream>>>(bufU, par, st, Ds + i * HH, bufAhi, bufAlo);
  }
  k_trans<<<OUTD * 512 / 256, 256, 0, stream>>>(Wo, OUTD, wth, wtl);
  k_gemm<0><<<dim3(OUTD / 128, BLM / 128), 256, 0, stream>>>(
      bufAhi, bufAlo, wth, wtl, bo, (float*)d_out, OUTD);
}

// Round 4
// 1188.500 us; speedup vs baseline: 1.5773x; 1.0185x over previous
//
#include <hip/hip_runtime.h>

#define BB 16
#define LL 2048
#define HH 512
#define NN2 32
#define NLAY 4
#define OUTD 256
#define BLM (BB*LL)                 // 32768 rows
#define NELEM ((size_t)BLM*HH)      // 16.78M activations
#define NC 16                       // SSM time chunks
#define LC (LL/NC)                  // 128
#define LGLC 7                      // log2(LC)

typedef __attribute__((ext_vector_type(8))) short s8v;   // 8 bf16 (4 VGPR)
typedef __attribute__((ext_vector_type(4))) float f4v;   // MFMA acc

__device__ __forceinline__ unsigned short f2bf(float f) {
  unsigned u = __float_as_uint(f);
  return (unsigned short)((u + 0x7fffu + ((u >> 16) & 1u)) >> 16);  // RNE
}
__device__ __forceinline__ float bf2f(unsigned short h) {
  return __uint_as_float((unsigned)h << 16);
}
__device__ __forceinline__ void gload16(const void* g, void* l) {
  __builtin_amdgcn_global_load_lds(
      (const __attribute__((address_space(1))) unsigned int*)g,
      (__attribute__((address_space(3))) unsigned int*)l, 16, 0, 0);
}

// ---------------- embedding gather -> bf16 hi/lo split ---------------------
__global__ __launch_bounds__(256) void k_embed(const int* __restrict__ x,
    const float* __restrict__ emb, unsigned short* __restrict__ Ahi,
    unsigned short* __restrict__ Alo) {
  int idx = blockIdx.x * 256 + threadIdx.x;      // one float4-group
  int j4 = idx & 127;
  int bl = idx >> 7;
  int tok = x[bl];
  float4 v = reinterpret_cast<const float4*>(emb)[tok * 128 + j4];
  unsigned short h0 = f2bf(v.x), h1 = f2bf(v.y), h2 = f2bf(v.z), h3 = f2bf(v.w);
  unsigned short l0 = f2bf(v.x - bf2f(h0)), l1 = f2bf(v.y - bf2f(h1));
  unsigned short l2 = f2bf(v.z - bf2f(h2)), l3 = f2bf(v.w - bf2f(h3));
  uint2 hp = make_uint2((unsigned)h0 | ((unsigned)h1 << 16),
                        (unsigned)h2 | ((unsigned)h3 << 16));
  uint2 lp = make_uint2((unsigned)l0 | ((unsigned)l1 << 16),
                        (unsigned)l2 | ((unsigned)l3 << 16));
  *reinterpret_cast<uint2*>(&Ahi[(size_t)idx * 4]) = hp;
  *reinterpret_cast<uint2*>(&Alo[(size_t)idx * 4]) = lp;
}

// ---------------- weight transpose + hi/lo split: Wt[n][k] = W[k][n] -------
__global__ __launch_bounds__(256) void k_trans(const float* __restrict__ W, int N,
    unsigned short* __restrict__ th, unsigned short* __restrict__ tl) {
  int t = blockIdx.x * 256 + threadIdx.x;        // over N*512, k fastest
  int k = t & 511, n = t >> 9;
  float v = W[(size_t)k * N + n];
  unsigned short hi = f2bf(v);
  th[(size_t)n * 512 + k] = hi;
  tl[(size_t)n * 512 + k] = f2bf(v - bf2f(hi));
}

// ---------------- per-layer SSM parameters ---------------------------------
__global__ __launch_bounds__(256) void k_params(const float* __restrict__ log_dt,
    const float* __restrict__ log_A_real, const float* __restrict__ A_imag,
    const float* __restrict__ C_re, const float* __restrict__ C_im,
    int layer, float4* __restrict__ par) {
  int idx = blockIdx.x * 256 + threadIdx.x;      // h*32+n
  int h = idx >> 5;
  int o = layer * HH * NN2 + idx;
  float dt  = expf(log_dt[layer * HH + h]);
  float Are = -expf(log_A_real[o]);
  float Aim = A_imag[o];
  float er = expf(Are * dt);
  float lr = er * cosf(Aim * dt), li = er * sinf(Aim * dt);
  float inv  = 1.0f / (Are * Are + Aim * Aim);
  float numr = lr - 1.0f, numi = li;
  float qr = (numr * Are + numi * Aim) * inv;
  float qi = (numi * Are - numr * Aim) * inv;
  float cr = C_re[o], ci = C_im[o];
  par[idx] = make_float4(lr, li, 2.0f * (cr * qr - ci * qi),
                                 2.0f * (cr * qi + ci * qr));
}

// ---------------- split-bf16 MFMA GEMM, 128x128 tile, BK=32, double-buffered
// C = A@W (+bias [+resid, act]) with A ~ Ahi+Alo, W ~ Bhi+Blo (B stored N x K).
// LDS fragment-ordered (frag f = 64 lanes x 16B, conflict-free ds_read_b128).
// 2-phase pipeline: stage tile kt+1 into the other buffer BEFORE computing
// tile kt, single __syncthreads per K-step -> loads overlap 48 MFMAs.
template<int EPI>
__global__ __launch_bounds__(256) void k_gemm(
    const unsigned short* __restrict__ Ahi, const unsigned short* __restrict__ Alo,
    const unsigned short* __restrict__ Bhi, const unsigned short* __restrict__ Blo,
    const float* __restrict__ bias, float* __restrict__ Out, int N) {
  __shared__ short lds[32768];                   // 64KB: 2 x (AH|AL|BH|BL)
  const int tid = threadIdx.x;
  const int lane = tid & 63, w = tid >> 6;
  const int wr = w >> 1, wc = w & 1;             // wave -> 64x64 quadrant
  const int m0 = blockIdx.y * 128, n0 = blockIdx.x * 128;
  const int lm = lane & 15, lk = lane >> 4;

  const unsigned short* ga[2][2]; const unsigned short* gb[2][2];
  short *da[2][2], *db[2][2];
#pragma unroll
  for (int f2 = 0; f2 < 2; ++f2) {
    int f = w * 2 + f2;                          // frag 0..7
    size_t ra = (size_t)(m0 + f * 16 + lm) * 512 + lk * 8;
    size_t rb = (size_t)(n0 + f * 16 + lm) * 512 + lk * 8;
    ga[0][f2] = Ahi + ra; ga[1][f2] = Alo + ra;
    gb[0][f2] = Bhi + rb; gb[1][f2] = Blo + rb;
    da[0][f2] = &lds[f * 512 + lane * 8];
    da[1][f2] = &lds[4096 + f * 512 + lane * 8];
    db[0][f2] = &lds[8192 + f * 512 + lane * 8];
    db[1][f2] = &lds[12288 + f * 512 + lane * 8];
  }
  f4v acc[4][4];
#pragma unroll
  for (int i = 0; i < 4; ++i)
#pragma unroll
    for (int j = 0; j < 4; ++j) acc[i][j] = (f4v){0.f, 0.f, 0.f, 0.f};

  auto stage = [&](int kt, int bofs) {
#pragma unroll
    for (int f2 = 0; f2 < 2; ++f2) {
      gload16(ga[0][f2] + kt * 32, da[0][f2] + bofs);
      gload16(ga[1][f2] + kt * 32, da[1][f2] + bofs);
      gload16(gb[0][f2] + kt * 32, db[0][f2] + bofs);
      gload16(gb[1][f2] + kt * 32, db[1][f2] + bofs);
    }
  };
  auto compute = [&](int bofs) {
    s8v ah[4], al[4], bh[4], bl[4];
#pragma unroll
    for (int i = 0; i < 4; ++i) {
      ah[i] = *(const s8v*)&lds[bofs + (wr * 4 + i) * 512 + lane * 8];
      al[i] = *(const s8v*)&lds[bofs + 4096 + (wr * 4 + i) * 512 + lane * 8];
      bh[i] = *(const s8v*)&lds[bofs + 8192 + (wc * 4 + i) * 512 + lane * 8];
      bl[i] = *(const s8v*)&lds[bofs + 12288 + (wc * 4 + i) * 512 + lane * 8];
    }
#pragma unroll
    for (int mi = 0; mi < 4; ++mi)
#pragma unroll
      for (int ni = 0; ni < 4; ++ni) {
        acc[mi][ni] = __builtin_amdgcn_mfma_f32_16x16x32_bf16(ah[mi], bh[ni], acc[mi][ni], 0, 0, 0);
        acc[mi][ni] = __builtin_amdgcn_mfma_f32_16x16x32_bf16(al[mi], bh[ni], acc[mi][ni], 0, 0, 0);
        acc[mi][ni] = __builtin_amdgcn_mfma_f32_16x16x32_bf16(ah[mi], bl[ni], acc[mi][ni], 0, 0, 0);
      }
  };

  stage(0, 0);
  __syncthreads();                               // tile 0 ready
#pragma unroll 1
  for (int t = 0; t < 8; ++t) {
    stage(2 * t + 1, 16384);                     // prefetch odd tile
    compute(0);                                  // compute even tile
    __syncthreads();                             // drains prefetch vmcnt
    if (t < 7) stage(2 * t + 2, 0);              // prefetch next even tile
    compute(16384);                              // compute odd tile
    __syncthreads();
  }
  // epilogue: C/D layout col=lane&15, row=(lane>>4)*4+reg
  float bb[4];
#pragma unroll
  for (int ni = 0; ni < 4; ++ni) bb[ni] = bias[n0 + wc * 64 + ni * 16 + lm];
#pragma unroll
  for (int mi = 0; mi < 4; ++mi) {
#pragma unroll
    for (int r = 0; r < 4; ++r) {
      int row = m0 + wr * 64 + mi * 16 + lk * 4 + r;
      float* po = Out + (size_t)row * N;
      const unsigned short* ph = Ahi + (size_t)row * 512;
      const unsigned short* pl = Alo + (size_t)row * 512;
#pragma unroll
      for (int ni = 0; ni < 4; ++ni) {
        int col = n0 + wc * 64 + ni * 16 + lm;
        float t = acc[mi][ni][r] + bb[ni];
        if (EPI) {
          t += bf2f(ph[col]) + bf2f(pl[col]);     // resid = hi+lo (err 2^-18)
          t = t < 0.f ? 2.f * t : 4.f * t;        // relu+res, x2
        }
        po[col] = t;
      }
    }
  }
}

// ---------------- SSM pass A: chunk-local raw states (chunks 0..NC-2) ------
__global__ __launch_bounds__(256) void k_sa(const float* __restrict__ U,
    const float4* __restrict__ par, float2* __restrict__ st) {
  int tid = threadIdx.x;
  int n = tid & 31, hs = tid >> 5;               // 8 h per block
  int hb = blockIdx.x, c = blockIdx.y, b = blockIdx.z;
  int h = (hb << 3) + hs;
  float4 p = par[(h << 5) + n];
  float lr = p.x, li = p.y;
  const float* Up = U + ((size_t)b * LL + (size_t)c * LC) * HH + h;
  float sr = 0.f, si = 0.f;
  auto step = [&](float uv) {
    float nsr = fmaf(lr, sr, fmaf(-li, si, uv));
    si = fmaf(lr, si, li * sr);
    sr = nsr;
  };
  float u0 = Up[0], u1 = Up[HH], u2 = Up[2 * HH], u3 = Up[3 * HH];
  for (int lg = 0; lg < LC / 4; ++lg) {
    const float* nx = Up + (size_t)(lg * 4 + 4) * HH;   // c<=NC-2: stays in U
    float v0 = nx[0], v1 = nx[HH], v2 = nx[2 * HH], v3 = nx[3 * HH];
    step(u0); step(u1); step(u2); step(u3);
    u0 = v0; u1 = v1; u2 = v2; u3 = v3;
  }
  st[(((size_t)b * (NC - 1) + c) * HH + h) * NN2 + n] = make_float2(sr, si);
}

// ---------------- fold: prefix-scan chunk states (in place, shifted) -------
// after: slot c holds raw state at START of chunk c+1.
__global__ __launch_bounds__(256) void k_fold(const float4* __restrict__ par,
    float2* __restrict__ st) {
  int t = blockIdx.x * 256 + threadIdx.x;        // b*16384 + h*32 + n
  int hn = t & 16383;
  int b = t >> 14;
  float4 p = par[hn];
  float ar = p.x, ai = p.y;
#pragma unroll
  for (int s = 0; s < LGLC; ++s) { float nr = ar * ar - ai * ai; ai = 2.f * ar * ai; ar = nr; }  // lam^LC
  float gr = 0.f, gi = 0.f;
  size_t idx = (size_t)b * (NC - 1) * 16384 + hn;
  for (int c = 0; c < NC - 1; ++c) {
    float2 s = st[idx + (size_t)c * 16384];
    float ngr = fmaf(ar, gr, fmaf(-ai, gi, s.x));
    gi = fmaf(ar, gi, fmaf(ai, gr, s.y));
    gr = ngr;
    st[idx + (size_t)c * 16384] = make_float2(gr, gi);
  }
}

// ---------------- SSM pass B: folded recurrence + epilogue -> bf16 hi/lo ---
// thread = (b, h, chunk, q); q owns 8 of 32 states; after the shfl reduce all
// 4 q-lanes hold the step's result, so lane q stores step q of each 4-group.
__global__ __launch_bounds__(256) void k_sb(const float* __restrict__ U,
    const float4* __restrict__ par, const float2* __restrict__ st,
    const float* __restrict__ D, unsigned short* __restrict__ Hhi,
    unsigned short* __restrict__ Hlo) {
  int tid = threadIdx.x;
  int q = tid & 3, hs = tid >> 2;                // 64 h per block, 4 q-lanes
  int hb = blockIdx.x, c = blockIdx.y, b = blockIdx.z;
  int h = (hb << 6) + hs;
  float lr[8], li[8], cr[8], ci[8], tr[8], ti[8];
#pragma unroll
  for (int j = 0; j < 8; ++j) {
    float4 p = par[(h << 5) + (q << 3) + j];
    lr[j] = p.x; li[j] = p.y; cr[j] = p.z; ci[j] = p.w;
    tr[j] = 0.f; ti[j] = 0.f;
  }
  if (c > 0) {
#pragma unroll
    for (int j = 0; j < 8; ++j) {
      float2 s = st[(((size_t)b * (NC - 1) + (c - 1)) * HH + h) * NN2 + (q << 3) + j];
      tr[j] = cr[j] * s.x - ci[j] * s.y;
      ti[j] = cr[j] * s.y + ci[j] * s.x;
    }
  }
  float dp1 = D[h] + 1.0f;
  size_t base = ((size_t)b * LL + (size_t)c * LC) * HH + h;
  const float* Up = U + base;
  auto step = [&](float uv) -> float {
    float ys = 0.f;
#pragma unroll
    for (int j = 0; j < 8; ++j) {
      float ntr = fmaf(lr[j], tr[j], fmaf(-li[j], ti[j], cr[j] * uv));
      ti[j] = fmaf(lr[j], ti[j], fmaf(li[j], tr[j], ci[j] * uv));
      tr[j] = ntr;
      ys += ntr;
    }
    ys += __shfl_xor(ys, 1);
    ys += __shfl_xor(ys, 2);
    float t4 = fmaf(dp1, uv, ys);
    return t4 < 0.f ? 2.f * t4 : 4.f * t4;
  };
  float u0 = Up[0], u1 = Up[HH], u2 = Up[2 * HH], u3 = Up[3 * HH];
  for (int lg = 0; lg < LC / 4; ++lg) {
    const float* nx = Up + (size_t)(lg * 4 + 4) * HH;  // tail prefetch lands in ws: harmless
    float v0 = nx[0], v1 = nx[HH], v2 = nx[2 * HH], v3 = nx[3 * HH];
    float r0 = step(u0), r1 = step(u1), r2 = step(u2), r3 = step(u3);
    // all q-lanes hold identical r0..r3; lane q stores step q's output
    float rq = q == 0 ? r0 : q == 1 ? r1 : q == 2 ? r2 : r3;
    size_t o = base + (size_t)(lg * 4 + q) * HH;
    unsigned short hi = f2bf(rq);
    Hhi[o] = hi;
    Hlo[o] = f2bf(rq - bf2f(hi));
    u0 = v0; u1 = v1; u2 = v2; u3 = v3;
  }
}

// ---------------------------------------------------------------------------
extern "C" void kernel_launch(void* const* d_in, const int* in_sizes, int n_in,
                              void* d_out, int out_size, void* d_ws, size_t ws_size,
                              hipStream_t stream) {
  const int*   x      = (const int*)d_in[0];
  const float* emb    = (const float*)d_in[1];
  const float* Ws     = (const float*)d_in[2];
  const float* bs     = (const float*)d_in[3];
  const float* log_dt = (const float*)d_in[4];
  const float* lAr    = (const float*)d_in[5];
  const float* Aim    = (const float*)d_in[6];
  const float* Cre    = (const float*)d_in[7];
  const float* Cim    = (const float*)d_in[8];
  const float* Ds     = (const float*)d_in[9];
  const float* Wo     = (const float*)d_in[10];
  const float* bo     = (const float*)d_in[11];

  float*          bufU   = (float*)d_ws;                       // 67.1 MB
  unsigned short* bufAhi = (unsigned short*)(bufU + NELEM);    // 33.6 MB
  unsigned short* bufAlo = bufAhi + NELEM;                     // 33.6 MB
  float4*         par    = (float4*)(bufAlo + NELEM);          // 256 KB
  float2*         st     = (float2*)(par + HH * NN2);          // 31.5 MB
  unsigned short* wth    = (unsigned short*)(st + (size_t)BB * (NC - 1) * HH * NN2);  // 512 KB
  unsigned short* wtl    = wth + 512 * 512;                    // 512 KB

  k_embed<<<(int)(NELEM / 4 / 256), 256, 0, stream>>>(x, emb, bufAhi, bufAlo);
  for (int i = 0; i < NLAY; ++i) {
    k_params<<<HH * NN2 / 256, 256, 0, stream>>>(log_dt, lAr, Aim, Cre, Cim, i, par);
    k_trans<<<HH * 512 / 256, 256, 0, stream>>>(Ws + (size_t)i * HH * HH, HH, wth, wtl);
    k_gemm<1><<<dim3(HH / 128, BLM / 128), 256, 0, stream>>>(
        bufAhi, bufAlo, wth, wtl, bs + i * HH, bufU, HH);
    k_sa<<<dim3(64, NC - 1, BB), 256, 0, stream>>>(bufU, par, st);
    k_fold<<<BB * HH * NN2 / 256, 256, 0, stream>>>(par, st);
    k_sb<<<dim3(8, NC, BB), 256, 0, stream>>>(bufU, par, st, Ds + i * HH, bufAhi, bufAlo);
  }
  k_trans<<<OUTD * 512 / 256, 256, 0, stream>>>(Wo, OUTD, wth, wtl);
  k_gemm<0><<<dim3(OUTD / 128, BLM / 128), 256, 0, stream>>>(
      bufAhi, bufAlo, wth, wtl, bo, (float*)d_out, OUTD);
}